// Round 2
// baseline (243.571 us; speedup 1.0000x reference)
//
#include <hip/hip_runtime.h>
#include <math.h>

#define NROWS 16384
#define INDIM 2048
#define NE 16
#define NW 16                    // waves per block
#define CHUNK 128                // k-columns staged per chunk
#define NCHUNK (INDIM / CHUNK)   // 16
#define KSUB (CHUNK / NW)        // 8 k per wave per chunk
#define PAD 129                  // row stride in LDS: (lane*129+k)%32 = (lane+k)%32 -> 2-way, free

__global__ __launch_bounds__(1024) void gate_kernel(
    const float* __restrict__ x,
    const float* __restrict__ W1,
    const float* __restrict__ W2,
    float* __restrict__ out)
{
    // xs (33024 B) and part (34816 B) are never live simultaneously -> alias
    __shared__ union {
        float xs[64][PAD];          // staged x chunk: [row][k], pad 129
        float part[NW / 2][64][17]; // pair-preadded partials
    } sh;
    __shared__ float hbuf[64][17];
    __shared__ float w2s[NE * NE];  // total static LDS ~ 40 KB

    const int tid  = threadIdx.x;
    const int lane = tid & 63;
    const int wv   = __builtin_amdgcn_readfirstlane(tid >> 6);
    const int row0 = blockIdx.x * 64;

    if (tid < 64) {  // stage W2 once (256 floats)
        ((float4*)w2s)[tid] = ((const float4*)W2)[tid];
    }

    // ---- staging coordinates: 2048 float4 per chunk, 2 per thread ----
    const int sr0 = tid >> 5;                 // rows 0..31
    const int sc0 = (tid & 31) * 4;           // cols 0..124 (float4-aligned)
    const int sr1 = (tid + 1024) >> 5;        // rows 32..63
    const int sc1 = sc0;
    const float* xblk = x + (size_t)row0 * INDIM;

    // preload chunk 0 into registers (coalesced: 32 consecutive float4 per row-segment)
    float4 ra = *(const float4*)(xblk + (size_t)sr0 * INDIM + sc0);
    float4 rb = *(const float4*)(xblk + (size_t)sr1 * INDIM + sc1);

    float acc[NE];
    #pragma unroll
    for (int e = 0; e < NE; ++e) acc[e] = 0.0f;

    for (int c = 0; c < NCHUNK; ++c) {
        if (c) __syncthreads();   // all readers of previous chunk done
        // write staged registers -> LDS (scalar b32; ~4-way conflict, cheap)
        sh.xs[sr0][sc0 + 0] = ra.x;
        sh.xs[sr0][sc0 + 1] = ra.y;
        sh.xs[sr0][sc0 + 2] = ra.z;
        sh.xs[sr0][sc0 + 3] = ra.w;
        sh.xs[sr1][sc1 + 0] = rb.x;
        sh.xs[sr1][sc1 + 1] = rb.y;
        sh.xs[sr1][sc1 + 2] = rb.z;
        sh.xs[sr1][sc1 + 3] = rb.w;
        __syncthreads();          // chunk c visible

        // issue prefetch of chunk c+1 now; it overlaps the compute below and
        // is only awaited at next iteration's LDS write
        if (c + 1 < NCHUNK) {
            ra = *(const float4*)(xblk + (size_t)sr0 * INDIM + (c + 1) * CHUNK + sc0);
            rb = *(const float4*)(xblk + (size_t)sr1 * INDIM + (c + 1) * CHUNK + sc1);
        }

        // compute: wave wv handles k-sub [wv*8, wv*8+8) of this chunk.
        // W1 addresses are wave-uniform -> s_load (scalar pipe).
        const float* w1c = W1 + c * CHUNK + wv * KSUB;
        #pragma unroll
        for (int j = 0; j < KSUB; ++j) {
            const float xv = sh.xs[lane][wv * KSUB + j];
            #pragma unroll
            for (int e = 0; e < NE; ++e)
                acc[e] = fmaf(xv, w1c[e * INDIM + j], acc[e]);
        }
    }

    __syncthreads();   // xs dead; safe to reuse aliased memory as `part`

    // ---- cross-wave reduction: pair pre-add (waves 8..15 add into 0..7) ----
    if (wv < NW / 2) {
        #pragma unroll
        for (int e = 0; e < NE; ++e) sh.part[wv][lane][e] = acc[e];
    }
    __syncthreads();
    if (wv >= NW / 2) {
        #pragma unroll
        for (int e = 0; e < NE; ++e) sh.part[wv - NW / 2][lane][e] += acc[e];
    }
    __syncthreads();

    // ---- reduce 8 partials + tanh -> hbuf ----
    {
        const int r = tid >> 4;
        const int e = tid & 15;
        float s = 0.0f;
        #pragma unroll
        for (int w = 0; w < NW / 2; ++w) s += sh.part[w][r][e];
        hbuf[r][e] = tanhf(s);
    }
    __syncthreads();

    // ---- per-row logits, sort, softmax, k policy, outputs ----
    if (tid < 64) {
        const int r   = tid;
        const int row = row0 + r;

        float hr[NE];
        #pragma unroll
        for (int e = 0; e < NE; ++e) hr[e] = hbuf[r][e];

        float v[NE];
        int   idx[NE];
        #pragma unroll
        for (int f = 0; f < NE; ++f) {
            float s = 0.0f;
            #pragma unroll
            for (int j = 0; j < 4; ++j) {
                const float4 w = ((const float4*)w2s)[f * 4 + j];
                s = fmaf(hr[4 * j + 0], w.x, s);
                s = fmaf(hr[4 * j + 1], w.y, s);
                s = fmaf(hr[4 * j + 2], w.z, s);
                s = fmaf(hr[4 * j + 3], w.w, s);
            }
            v[f]   = s / 0.7f;   // logits
            idx[f] = f;
        }

        // bitonic sort on key (-value, index): stable descending argsort
        #pragma unroll
        for (int ksz = 2; ksz <= 16; ksz <<= 1) {
            #pragma unroll
            for (int jsz = ksz >> 1; jsz >= 1; jsz >>= 1) {
                #pragma unroll
                for (int i = 0; i < 16; ++i) {
                    const int l = i ^ jsz;
                    if (l > i) {
                        const bool asc   = ((i & ksz) == 0);
                        const bool keyGt = (v[i] < v[l]) ||
                                           (v[i] == v[l] && idx[i] > idx[l]);
                        if (keyGt == asc) {
                            float tv = v[i]; v[i] = v[l]; v[l] = tv;
                            int   ti = idx[i]; idx[i] = idx[l]; idx[l] = ti;
                        }
                    }
                }
            }
        }

        // softmax over sorted logits
        float p[NE];
        float tot = 0.0f;
        #pragma unroll
        for (int i = 0; i < NE; ++i) { p[i] = expf(v[i] - v[0]); tot += p[i]; }
        #pragma unroll
        for (int i = 0; i < NE; ++i) p[i] = p[i] / tot;

        float cum[NE];
        cum[0] = p[0];
        #pragma unroll
        for (int i = 1; i < NE; ++i) cum[i] = cum[i - 1] + p[i];

        int k = NE;
        #pragma unroll
        for (int i = NE - 1; i >= 0; --i) if (cum[i] >= 0.92f) k = i + 1;

        if ((p[0] >= 0.46f) && ((p[0] - p[1]) >= 0.1f)) k = 1;
        if ((k > 2) && ((cum[1] >= 0.82f) || (p[2] <= 0.12f) || ((p[1] - p[2]) <= 0.03f)))
            k = 2;
        k = k < 1 ? 1 : (k > 3 ? 3 : k);

        const float4 o0 = make_float4((float)idx[0], (float)idx[1], (float)idx[2], (float)idx[3]);
        const float4 o1 = make_float4((float)idx[4], (float)idx[5], (float)idx[6], (float)idx[7]);
        const float4 s0 = make_float4(k > 0 ? p[0] : 0.0f, k > 1 ? p[1] : 0.0f,
                                      k > 2 ? p[2] : 0.0f, k > 3 ? p[3] : 0.0f);
        const float4 s1 = make_float4(k > 4 ? p[4] : 0.0f, k > 5 ? p[5] : 0.0f,
                                      k > 6 ? p[6] : 0.0f, k > 7 ? p[7] : 0.0f);
        const float4 m0 = make_float4(k > 0 ? 1.0f : 0.0f, k > 1 ? 1.0f : 0.0f,
                                      k > 2 ? 1.0f : 0.0f, k > 3 ? 1.0f : 0.0f);
        const float4 m1 = make_float4(k > 4 ? 1.0f : 0.0f, k > 5 ? 1.0f : 0.0f,
                                      k > 6 ? 1.0f : 0.0f, k > 7 ? 1.0f : 0.0f);

        float4* oI = (float4*)(out + (size_t)row * 8);
        float4* oS = (float4*)(out + (size_t)NROWS * 8  + (size_t)row * 8);
        float4* oM = (float4*)(out + (size_t)NROWS * 16 + (size_t)row * 8);
        oI[0] = o0; oI[1] = o1;
        oS[0] = s0; oS[1] = s1;
        oM[0] = m0; oM[1] = m1;
        out[(size_t)NROWS * 24 + row] = (float)k;
    }
}

extern "C" void kernel_launch(void* const* d_in, const int* in_sizes, int n_in,
                              void* d_out, int out_size, void* d_ws, size_t ws_size,
                              hipStream_t stream)
{
    const float* x  = (const float*)d_in[0];
    const float* W1 = (const float*)d_in[1];
    const float* W2 = (const float*)d_in[2];
    gate_kernel<<<NROWS / 64, 1024, 0, stream>>>(x, W1, W2, (float*)d_out);
}

// Round 3
// 216.566 us; speedup vs baseline: 1.1247x; 1.1247x over previous
//
#include <hip/hip_runtime.h>
#include <math.h>

#define NROWS 16384
#define INDIM 2048
#define NE 16
#define RPB 16                    // rows per block (4 waves x 4 rows)
#define RPW 4                     // rows per wave
#define KSTEP 256                 // k covered per iteration (64 lanes x float4)
#define NITER (INDIM / KSTEP)     // 8

__global__ __launch_bounds__(256, 3) void gate_kernel(
    const float* __restrict__ x,
    const float* __restrict__ W1,
    const float* __restrict__ W2,
    float* __restrict__ out)
{
    __shared__ float hbuf[RPB][17];
    __shared__ float w2s[NE * NE];

    const int tid  = threadIdx.x;
    const int lane = tid & 63;
    const int wv   = tid >> 6;                       // 0..3
    const int rowW = blockIdx.x * RPB + wv * RPW;    // wave's first row

    if (tid < 64) ((float4*)w2s)[tid] = ((const float4*)W2)[tid];

    // acc[r*16+e]: this lane's k-partial for (row r, expert e)
    float acc[RPW * NE];
    #pragma unroll
    for (int i = 0; i < RPW * NE; ++i) acc[i] = 0.0f;

    const float* xw  = x  + (size_t)rowW * INDIM + lane * 4;  // per-lane, coalesced
    const float* w1l = W1 + lane * 4;                          // per-lane, coalesced

    #pragma unroll 1
    for (int it = 0; it < NITER; ++it) {
        const int k0 = it * KSTEP;
        float4 xv[RPW];
        #pragma unroll
        for (int r = 0; r < RPW; ++r)
            xv[r] = *(const float4*)(xw + (size_t)r * INDIM + k0);

        #pragma unroll
        for (int eh = 0; eh < 2; ++eh) {           // experts in halves of 8 (VGPR pressure)
            float4 wq[8];
            #pragma unroll
            for (int e = 0; e < 8; ++e)
                wq[e] = *(const float4*)(w1l + (size_t)(eh * 8 + e) * INDIM + k0);
            #pragma unroll
            for (int r = 0; r < RPW; ++r) {
                #pragma unroll
                for (int e = 0; e < 8; ++e) {
                    float a = acc[r * NE + eh * 8 + e];
                    a = fmaf(xv[r].x, wq[e].x, a);
                    a = fmaf(xv[r].y, wq[e].y, a);
                    a = fmaf(xv[r].z, wq[e].z, a);
                    a = fmaf(xv[r].w, wq[e].w, a);
                    acc[r * NE + eh * 8 + e] = a;
                }
            }
        }
    }

    // ---- folding butterfly: reduce 64 values across 64 lanes in 63 shuffles.
    // After step s (mask 1<<s), lane keeps the half of its value-set selected by
    // its lane-bit s; final: lane L holds the full sum of value bitrev6(L).
    #pragma unroll
    for (int s = 0; s < 6; ++s) {
        const int m = 1 << s;
        const int h = 32 >> s;
        const int b = (lane >> s) & 1;
        #pragma unroll
        for (int i = 0; i < h; ++i) {
            const float keep = b ? acc[i + h] : acc[i];
            const float send = b ? acc[i] : acc[i + h];
            acc[i] = keep + __shfl_xor(send, m, 64);
        }
    }
    {
        int v = 0;
        #pragma unroll
        for (int s = 0; s < 6; ++s) v |= ((lane >> s) & 1) << (5 - s);
        hbuf[wv * RPW + (v >> 4)][v & 15] = tanhf(acc[0]);
    }
    __syncthreads();

    // ---- per-row tail: logits, sort, softmax, k policy, outputs ----
    if (tid < RPB) {
        const int r   = tid;
        const int row = blockIdx.x * RPB + r;

        float hr[NE];
        #pragma unroll
        for (int e = 0; e < NE; ++e) hr[e] = hbuf[r][e];

        float v[NE];
        int   idx[NE];
        #pragma unroll
        for (int f = 0; f < NE; ++f) {
            float s = 0.0f;
            #pragma unroll
            for (int j = 0; j < 4; ++j) {
                const float4 w = ((const float4*)w2s)[f * 4 + j];
                s = fmaf(hr[4 * j + 0], w.x, s);
                s = fmaf(hr[4 * j + 1], w.y, s);
                s = fmaf(hr[4 * j + 2], w.z, s);
                s = fmaf(hr[4 * j + 3], w.w, s);
            }
            v[f]   = s / 0.7f;
            idx[f] = f;
        }

        // bitonic sort on key (-value, index): stable descending argsort
        #pragma unroll
        for (int ksz = 2; ksz <= 16; ksz <<= 1) {
            #pragma unroll
            for (int jsz = ksz >> 1; jsz >= 1; jsz >>= 1) {
                #pragma unroll
                for (int i = 0; i < 16; ++i) {
                    const int l = i ^ jsz;
                    if (l > i) {
                        const bool asc   = ((i & ksz) == 0);
                        const bool keyGt = (v[i] < v[l]) ||
                                           (v[i] == v[l] && idx[i] > idx[l]);
                        if (keyGt == asc) {
                            float tv = v[i]; v[i] = v[l]; v[l] = tv;
                            int   ti = idx[i]; idx[i] = idx[l]; idx[l] = ti;
                        }
                    }
                }
            }
        }

        float p[NE];
        float tot = 0.0f;
        #pragma unroll
        for (int i = 0; i < NE; ++i) { p[i] = expf(v[i] - v[0]); tot += p[i]; }
        #pragma unroll
        for (int i = 0; i < NE; ++i) p[i] = p[i] / tot;

        float cum[NE];
        cum[0] = p[0];
        #pragma unroll
        for (int i = 1; i < NE; ++i) cum[i] = cum[i - 1] + p[i];

        int k = NE;
        #pragma unroll
        for (int i = NE - 1; i >= 0; --i) if (cum[i] >= 0.92f) k = i + 1;

        if ((p[0] >= 0.46f) && ((p[0] - p[1]) >= 0.1f)) k = 1;
        if ((k > 2) && ((cum[1] >= 0.82f) || (p[2] <= 0.12f) || ((p[1] - p[2]) <= 0.03f)))
            k = 2;
        k = k < 1 ? 1 : (k > 3 ? 3 : k);

        const float4 o0 = make_float4((float)idx[0], (float)idx[1], (float)idx[2], (float)idx[3]);
        const float4 o1 = make_float4((float)idx[4], (float)idx[5], (float)idx[6], (float)idx[7]);
        const float4 s0 = make_float4(k > 0 ? p[0] : 0.0f, k > 1 ? p[1] : 0.0f,
                                      k > 2 ? p[2] : 0.0f, k > 3 ? p[3] : 0.0f);
        const float4 s1 = make_float4(k > 4 ? p[4] : 0.0f, k > 5 ? p[5] : 0.0f,
                                      k > 6 ? p[6] : 0.0f, k > 7 ? p[7] : 0.0f);
        const float4 m0 = make_float4(k > 0 ? 1.0f : 0.0f, k > 1 ? 1.0f : 0.0f,
                                      k > 2 ? 1.0f : 0.0f, k > 3 ? 1.0f : 0.0f);
        const float4 m1 = make_float4(k > 4 ? 1.0f : 0.0f, k > 5 ? 1.0f : 0.0f,
                                      k > 6 ? 1.0f : 0.0f, k > 7 ? 1.0f : 0.0f);

        float4* oI = (float4*)(out + (size_t)row * 8);
        float4* oS = (float4*)(out + (size_t)NROWS * 8  + (size_t)row * 8);
        float4* oM = (float4*)(out + (size_t)NROWS * 16 + (size_t)row * 8);
        oI[0] = o0; oI[1] = o1;
        oS[0] = s0; oS[1] = s1;
        oM[0] = m0; oM[1] = m1;
        out[(size_t)NROWS * 24 + row] = (float)k;
    }
}

extern "C" void kernel_launch(void* const* d_in, const int* in_sizes, int n_in,
                              void* d_out, int out_size, void* d_ws, size_t ws_size,
                              hipStream_t stream)
{
    const float* x  = (const float*)d_in[0];
    const float* W1 = (const float*)d_in[1];
    const float* W2 = (const float*)d_in[2];
    gate_kernel<<<NROWS / RPB, 256, 0, stream>>>(x, W1, W2, (float*)d_out);
}